// Round 3
// baseline (364.508 us; speedup 1.0000x reference)
//
#include <hip/hip_runtime.h>
#include <stdint.h>

// Gaussian kernel matrix K[i][j] = exp(-||x_i-x_j||^2/2), X: [16384][64] fp32.
// R3: software-pipelined B prefetch. Raw f32 B loads for tile t+1 are issued
// AFTER the MFMA but BEFORE the epilogue stores of tile t, so the vmcnt wait
// for them does not have to drain the (slow, write-bound) stores. Epilogue
// strength-reduced: arg = hA + hcol + log2(e)*dot, one add + one fma + v_exp.
// Nontemporal stores keep L2 clean for the X reads.

typedef __attribute__((ext_vector_type(8))) short s16x8;   // 8 bf16 (MFMA A/B frag)
typedef __attribute__((ext_vector_type(4))) float f32x4;

#define DDIM 64
#define JT 8
#define LOG2E      1.4426950408889634f   // 2c
#define HALF_LOG2E 0.7213475204444817f   // c ; K = exp2(-c*(||i||^2+||j||^2) + 2c*dot)

// fp32 -> bf16 RNE on the bit pattern; accumulates rounded value^2 for norms.
__device__ inline short cvt1(float x, float& sq) {
  uint32_t u = __builtin_bit_cast(uint32_t, x);
  uint32_t r = (u + 0x7fffu + ((u >> 16) & 1u)) & 0xffff0000u;
  float hf = __builtin_bit_cast(float, r);
  sq += hf * hf;
  return (short)(r >> 16);
}

// Issue the 4 dwordx4 loads for one fragment row (row, k-chunk lq*8 within each
// 32-wide k-step). No conversion here — keeps the loads free to overlap stores.
__device__ inline void issue_row(const float* __restrict__ X, int row, int lq,
                                 f32x4 r[4]) {
  const f32x4* p = reinterpret_cast<const f32x4*>(X + (size_t)row * DDIM + lq * 8);
  const f32x4* q = reinterpret_cast<const f32x4*>(X + (size_t)row * DDIM + 32 + lq * 8);
  r[0] = p[0]; r[1] = p[1]; r[2] = q[0]; r[3] = q[1];
}

// Convert raw f32 row data to bf16 MFMA fragments + premultiplied norm (-c*||x||^2).
__device__ inline void cvt_row(const f32x4 r[4], s16x8 h[2], float& hnorm) {
  float s = 0.f;
#pragma unroll
  for (int ks = 0; ks < 2; ++ks) {
    s16x8 hh;
    hh[0] = cvt1(r[2*ks][0], s);   hh[1] = cvt1(r[2*ks][1], s);
    hh[2] = cvt1(r[2*ks][2], s);   hh[3] = cvt1(r[2*ks][3], s);
    hh[4] = cvt1(r[2*ks+1][0], s); hh[5] = cvt1(r[2*ks+1][1], s);
    hh[6] = cvt1(r[2*ks+1][2], s); hh[7] = cvt1(r[2*ks+1][3], s);
    h[ks] = hh;
  }
  s += __shfl_xor(s, 16);
  s += __shfl_xor(s, 32);
  hnorm = -HALF_LOG2E * s;
}

__global__ __launch_bounds__(256, 2) void gauss_gram_kernel(
    const float* __restrict__ X, float* __restrict__ K, int n) {
  const int lane = threadIdx.x & 63;
  const int wid  = threadIdx.x >> 6;   // 4 waves: 2x2 over the 128x128 tile
  const int wr = wid >> 1;
  const int wc = wid & 1;
  const int l15 = lane & 15;
  const int lq  = lane >> 4;           // 0..3

  const int i0     = blockIdx.x * 128 + wr * 64;   // output row base (this wave)
  const int jstrip = blockIdx.y * (128 * JT);      // column strip base

  // ---- prologue: issue A loads, then B(jt=0) loads; cvt A while B flies ----
  f32x4 araw[4][4];
#pragma unroll
  for (int mi = 0; mi < 4; ++mi)
    issue_row(X, i0 + mi * 16 + l15, lq, araw[mi]);

  f32x4 braw[4][4];
#pragma unroll
  for (int ni = 0; ni < 4; ++ni)
    issue_row(X, jstrip + wc * 64 + ni * 16 + l15, lq, braw[ni]);

  s16x8 a[4][2]; float hA[4];
#pragma unroll
  for (int mi = 0; mi < 4; ++mi)
    cvt_row(araw[mi], a[mi], hA[mi]);
  // hA[mi] at lane l is -c*||row (i0+mi*16+l15)||^2 == this lane's output row. No shfl.

#pragma unroll
  for (int jt = 0; jt < JT; ++jt) {
    const int j0 = jstrip + jt * 128 + wc * 64;

    // ---- cvt current B (waits only for the braw loads, not older stores) ----
    s16x8 b[4][2]; float hcol[4][4];
#pragma unroll
    for (int ni = 0; ni < 4; ++ni) {
      float hB;
      cvt_row(braw[ni], b[ni], hB);
#pragma unroll
      for (int r = 0; r < 4; ++r)
        hcol[ni][r] = __shfl(hB, lq * 4 + r);   // -c*norm of output col j0+ni*16+lq*4+r
    }

    // ---- MFMA, swapped operands: lane's 4 acc regs = 4 consecutive output cols ----
    f32x4 acc[4][4] = {};
#pragma unroll
    for (int ks = 0; ks < 2; ++ks)
#pragma unroll
      for (int mi = 0; mi < 4; ++mi)
#pragma unroll
        for (int ni = 0; ni < 4; ++ni)
          acc[mi][ni] = __builtin_amdgcn_mfma_f32_16x16x32_bf16(
              b[ni][ks], a[mi][ks], acc[mi][ni], 0, 0, 0);

    // ---- prefetch next tile's B (issue BEFORE the stores below) ----
    if (jt + 1 < JT) {
#pragma unroll
      for (int ni = 0; ni < 4; ++ni)
        issue_row(X, jstrip + (jt + 1) * 128 + wc * 64 + ni * 16 + l15, lq, braw[ni]);
    }
    __builtin_amdgcn_sched_barrier(0);  // pin: loads above, stores below

    // ---- epilogue: arg = hA + hcol + log2e*dot (<=0); K = exp2(arg) ----
#pragma unroll
    for (int mi = 0; mi < 4; ++mi) {
      const int rg = i0 + mi * 16 + l15;
      float* rowp = K + (size_t)rg * n;
#pragma unroll
      for (int ni = 0; ni < 4; ++ni) {
        const int c0 = j0 + ni * 16 + lq * 4;
        f32x4 v;
#pragma unroll
        for (int r = 0; r < 4; ++r) {
          float arg = fminf(hA[mi] + hcol[ni][r] + LOG2E * acc[mi][ni][r], 0.0f);
          float e = exp2f(arg);
          v[r] = (rg == c0 + r) ? 1.0f : e;   // exact diagonal
        }
        __builtin_nontemporal_store(v, reinterpret_cast<f32x4*>(rowp + c0));
      }
    }
  }
}

extern "C" void kernel_launch(void* const* d_in, const int* in_sizes, int n_in,
                              void* d_out, int out_size, void* d_ws, size_t ws_size,
                              hipStream_t stream) {
  (void)n_in; (void)d_ws; (void)ws_size; (void)out_size;
  const float* X = (const float*)d_in[0];
  float* K = (float*)d_out;
  const int n = in_sizes[0] / DDIM;          // 16384
  dim3 grid(n / 128, n / (128 * JT));        // (128, 16)
  gauss_gram_kernel<<<grid, 256, 0, stream>>>(X, K, n);
}

// Round 4
// 252.722 us; speedup vs baseline: 1.4423x; 1.4423x over previous
//
#include <hip/hip_runtime.h>
#include <stdint.h>

// Gaussian kernel matrix K[i][j] = exp(-||x_i-x_j||^2/2), X: [16384][64] fp32.
// R4: R2 structure + clean store/load decoupling. Next-tile B loads are issued
// BEFORE this tile's stores (vmcnt FIFO: loads older than stores, so the next
// iteration's cvt waits only on the loads and leaves all 16 stores in flight).
// Unlike R3: NO nontemporal stores, and sched_barrier(0xF) only pins VMEM
// order (VALU/MFMA may cross and interleave freely).

typedef __attribute__((ext_vector_type(8))) short s16x8;   // 8 bf16 (MFMA A/B frag)
typedef __attribute__((ext_vector_type(4))) float f32x4;

#define DDIM 64
#define JT 8
#define LOG2E      1.4426950408889634f   // 2c
#define HALF_LOG2E 0.7213475204444817f   // c ; K = exp2(-c*||i||^2 - c*||j||^2 + 2c*dot)

// fp32 -> bf16 RNE on the bit pattern; accumulates rounded value^2 for norms.
__device__ inline short cvt1(float x, float& sq) {
  uint32_t u = __builtin_bit_cast(uint32_t, x);
  uint32_t r = (u + 0x7fffu + ((u >> 16) & 1u)) & 0xffff0000u;
  float hf = __builtin_bit_cast(float, r);
  sq += hf * hf;
  return (short)(r >> 16);
}

// Issue the 4 dwordx4 loads for one fragment row (row, k-chunk lq*8 in each
// 32-wide k-step). Raw loads only — conversion happens later so these can fly
// while other work proceeds.
__device__ inline void issue_row(const float* __restrict__ X, int row, int lq,
                                 f32x4 r[4]) {
  const f32x4* p = reinterpret_cast<const f32x4*>(X + (size_t)row * DDIM + lq * 8);
  const f32x4* q = reinterpret_cast<const f32x4*>(X + (size_t)row * DDIM + 32 + lq * 8);
  r[0] = p[0]; r[1] = p[1]; r[2] = q[0]; r[3] = q[1];
}

// Raw f32 row data -> bf16 MFMA fragments + premultiplied norm (-c*||x||^2).
__device__ inline void cvt_row(const f32x4 r[4], s16x8 h[2], float& hnorm) {
  float s = 0.f;
#pragma unroll
  for (int ks = 0; ks < 2; ++ks) {
    s16x8 hh;
    hh[0] = cvt1(r[2*ks][0], s);   hh[1] = cvt1(r[2*ks][1], s);
    hh[2] = cvt1(r[2*ks][2], s);   hh[3] = cvt1(r[2*ks][3], s);
    hh[4] = cvt1(r[2*ks+1][0], s); hh[5] = cvt1(r[2*ks+1][1], s);
    hh[6] = cvt1(r[2*ks+1][2], s); hh[7] = cvt1(r[2*ks+1][3], s);
    h[ks] = hh;
  }
  s += __shfl_xor(s, 16);
  s += __shfl_xor(s, 32);
  hnorm = -HALF_LOG2E * s;
}

__global__ __launch_bounds__(256, 2) void gauss_gram_kernel(
    const float* __restrict__ X, float* __restrict__ K, int n) {
  const int lane = threadIdx.x & 63;
  const int wid  = threadIdx.x >> 6;   // 4 waves: 2x2 over the 128x128 tile
  const int wr = wid >> 1;
  const int wc = wid & 1;
  const int l15 = lane & 15;
  const int lq  = lane >> 4;           // 0..3

  const int i0     = blockIdx.x * 128 + wr * 64;   // output row base (this wave)
  const int jstrip = blockIdx.y * (128 * JT);      // column strip base

  // ---- prologue: issue A loads, then B(jt=0) loads; cvt A while B flies ----
  f32x4 araw[4][4];
#pragma unroll
  for (int mi = 0; mi < 4; ++mi)
    issue_row(X, i0 + mi * 16 + l15, lq, araw[mi]);

  f32x4 braw[4][4];
#pragma unroll
  for (int ni = 0; ni < 4; ++ni)
    issue_row(X, jstrip + wc * 64 + ni * 16 + l15, lq, braw[ni]);

  s16x8 a[4][2]; float hA[4];
#pragma unroll
  for (int mi = 0; mi < 4; ++mi)
    cvt_row(araw[mi], a[mi], hA[mi]);
  // hA[mi] at lane l is -c*||row (i0+mi*16+l15)||^2 == this lane's output row. No shfl.

#pragma unroll
  for (int jt = 0; jt < JT; ++jt) {
    const int j0 = jstrip + jt * 128 + wc * 64;

    // ---- cvt current B (waits only on braw loads: they are older than any
    //      outstanding stores in the vmcnt FIFO) ----
    s16x8 b[4][2]; float hcol[4][4];
#pragma unroll
    for (int ni = 0; ni < 4; ++ni) {
      float hB;
      cvt_row(braw[ni], b[ni], hB);
#pragma unroll
      for (int r = 0; r < 4; ++r)
        hcol[ni][r] = __shfl(hB, lq * 4 + r);   // -c*norm of output col j0+ni*16+lq*4+r
    }

    // ---- prefetch next tile's B now (ahead of this tile's stores) ----
    if (jt + 1 < JT) {
#pragma unroll
      for (int ni = 0; ni < 4; ++ni)
        issue_row(X, jstrip + (jt + 1) * 128 + wc * 64 + ni * 16 + l15, lq, braw[ni]);
    }
    // Pin VMEM order only: loads above may not sink, stores below may not
    // hoist. VALU/SALU/MFMA may cross freely for interleaving.
    __builtin_amdgcn_sched_barrier(0x2 | 0x4 | 0x8 | 0x1);

    // ---- MFMA, swapped operands: lane's 4 acc regs = 4 consecutive output cols ----
    f32x4 acc[4][4] = {};
#pragma unroll
    for (int ks = 0; ks < 2; ++ks)
#pragma unroll
      for (int mi = 0; mi < 4; ++mi)
#pragma unroll
        for (int ni = 0; ni < 4; ++ni)
          acc[mi][ni] = __builtin_amdgcn_mfma_f32_16x16x32_bf16(
              b[ni][ks], a[mi][ks], acc[mi][ni], 0, 0, 0);

    // ---- epilogue: arg = hA + hcol + 2c*dot (<=0); K = exp2(arg) ----
#pragma unroll
    for (int mi = 0; mi < 4; ++mi) {
      const int rg = i0 + mi * 16 + l15;
      float* rowp = K + (size_t)rg * n;
#pragma unroll
      for (int ni = 0; ni < 4; ++ni) {
        const int c0 = j0 + ni * 16 + lq * 4;
        f32x4 v;
#pragma unroll
        for (int r = 0; r < 4; ++r) {
          float arg = fminf(hA[mi] + hcol[ni][r] + LOG2E * acc[mi][ni][r], 0.0f);
          float e = exp2f(arg);
          v[r] = (rg == c0 + r) ? 1.0f : e;   // exact diagonal
        }
        *reinterpret_cast<f32x4*>(rowp + c0) = v;
      }
    }
  }
}

extern "C" void kernel_launch(void* const* d_in, const int* in_sizes, int n_in,
                              void* d_out, int out_size, void* d_ws, size_t ws_size,
                              hipStream_t stream) {
  (void)n_in; (void)d_ws; (void)ws_size; (void)out_size;
  const float* X = (const float*)d_in[0];
  float* K = (float*)d_out;
  const int n = in_sizes[0] / DDIM;          // 16384
  dim3 grid(n / 128, n / (128 * JT));        // (128, 16)
  gauss_gram_kernel<<<grid, 256, 0, stream>>>(X, K, n);
}